// Round 21
// baseline (421.658 us; speedup 1.0000x reference)
//
#include <hip/hip_runtime.h>
#include <hip/hip_bf16.h>
#include <cmath>

#define DIM 512
#define HID 256
#define ROWS_PB 16       // rows per block (100000 = 6250 * 16, no tail)
#define NCHUNK 16        // K chunks of 32
#define CB 16384         // B chunk bytes: 32k * 256c * 2B

typedef __attribute__((ext_vector_type(8))) short short8;
typedef __attribute__((ext_vector_type(4))) float f32x4;

#define AS1 __attribute__((address_space(1)))
#define AS3 __attribute__((address_space(3)))

__device__ __forceinline__ unsigned short f2bf(float f) {
  union { float f; unsigned u; } v; v.f = f;
  unsigned u = v.u;
  return (unsigned short)((u + 0x7FFFu + ((u >> 16) & 1u)) >> 16);
}

// Pre-swizzle W1 (fp32 [512,256] row-major) into bf16 MFMA fragment order:
// w1s[((k>>3)*HID + c)*8 + (k&7)]. K-chunk c (32 k's) is the contiguous
// 16 KB at byte offset c*16384 — a linear global_load_lds copy.
__global__ void w1_swz_kernel(const float* __restrict__ W1,
                              unsigned short* __restrict__ w1s) {
  int tid = blockIdx.x * blockDim.x + threadIdx.x;
  if (tid >= DIM * HID) return;
  int k = tid / HID;
  int c = tid - k * HID;
  w1s[(((k >> 3) * HID) + c) * 8 + (k & 7)] = f2bf(W1[tid]);
}

__device__ __forceinline__ short8 cvt8(const f32x4 p0, const f32x4 p1) {
  short8 r;
  r[0] = (short)f2bf(p0[0]); r[1] = (short)f2bf(p0[1]);
  r[2] = (short)f2bf(p0[2]); r[3] = (short)f2bf(p0[3]);
  r[4] = (short)f2bf(p1[0]); r[5] = (short)f2bf(p1[1]);
  r[6] = (short)f2bf(p1[2]); r[7] = (short)f2bf(p1[3]);
  return r;
}

// 8 waves / 16 rows. Wave w: src s=w&1, hid-QUARTER q=w>>1 (64 cols).
// Small per-wave state (acc 16 + af 64 + working ~30 < 128 cap) so TWO
// 512-thread blocks co-reside: 16 waves/CU (4/SIMD) — 2x any prior round —
// to latency-hide the per-chunk staging drain with pure TLP.
// A: af[16] regs, burst-loaded in 4-chunk groups (bounded transients).
// B: global_load_lds double buffer, ONE __syncthreads per chunk.
// K-loop: L2-only, 4 ds_read + 4 MFMA per chunk per wave.
// Epilogue: z re-read from L2-hot lines, fp32 end-to-end.
__global__ __launch_bounds__(512, 2) void fa_main_kernel(
    const float* __restrict__ z1, const float* __restrict__ z2,
    const unsigned short* __restrict__ w1s,
    const float* __restrict__ bias1, const float* __restrict__ W2,
    const float* __restrict__ bias2, float* __restrict__ out, int n) {
  __shared__ char smem[2 * CB + 512];     // B dbuf 32 KB; xs2 @ +32768
  float* xs2 = (float*)(smem + 2 * CB);   // [(s*4+q)][16 rows]

  const int t = threadIdx.x;
  const int w = t >> 6;
  const int l = t & 63;
  const int l15 = l & 15, l16 = l >> 4;
  const int s = w & 1;   // source this wave scores
  const int q = w >> 1;  // hid-quarter (64 cols) this wave computes
  const int row0 = blockIdx.x * ROWS_PB;
  int myrow = row0 + l15;
  const bool rok = myrow < n;
  if (!rok) myrow = n - 1;
  const float* zz = s ? z2 : z1;
  const float* ap = zz + (size_t)myrow * DIM + (l16 << 3);
  const f32x4 zf4 = (f32x4){0.f, 0.f, 0.f, 0.f};

  auto STAGE = [&](int cc, int buf) {
    const char* gsrc = (const char*)w1s + cc * CB + l * 16;
    char* ldst = smem + buf * CB;
#pragma unroll
    for (int r = 0; r < 2; ++r) {
      const int rr = w + r * 8;
      __builtin_amdgcn_global_load_lds(
          (const AS1 void*)(gsrc + rr * 1024),
          (AS3 void*)(ldst + rr * 1024), 16, 0, 0);
    }
  };

  // B[0] first (L2 latency overlaps the A burst), then A in 4 groups of 4
  // chunks (32 VGPR transient per group — bounded, anti-spill).
  STAGE(0, 0);
  __builtin_amdgcn_sched_barrier(0);
  short8 af[NCHUNK];
#pragma unroll
  for (int g = 0; g < 4; ++g) {
    f32x4 p[4][2];
#pragma unroll
    for (int j = 0; j < 4; ++j) {
      const float* pp = ap + (((g << 2) + j) << 5);
      p[j][0] = rok ? *(const f32x4*)(pp) : zf4;
      p[j][1] = rok ? *(const f32x4*)(pp + 4) : zf4;
    }
#pragma unroll
    for (int j = 0; j < 4; ++j) af[(g << 2) + j] = cvt8(p[j][0], p[j][1]);
  }

  f32x4 acc[4];
#pragma unroll
  for (int f = 0; f < 4; ++f) acc[f] = zf4;

  __syncthreads();  // B[0] staged (A burst also drained)

  // K-loop: STAGE(c+1) -> 4 ds_read + 4 MFMA -> ONE sync per chunk.
  // STAGE(c+1) writes buf (c+1)&1, last read at chunk c-1 and protected by
  // that chunk's barrier — same proven discipline as R20's loop.
#pragma unroll
  for (int c = 0; c < NCHUNK; ++c) {
    if (c + 1 < NCHUNK) STAGE(c + 1, (c + 1) & 1);
    __builtin_amdgcn_sched_barrier(0);  // pin stage issue above compute
    const short8* bp =
        (const short8*)(smem + (c & 1) * CB) + (l16 << 8) + (q << 6) + l15;
#pragma unroll
    for (int f = 0; f < 4; ++f)
      acc[f] = __builtin_amdgcn_mfma_f32_16x16x32_bf16(af[c], bp[f << 4],
                                                       acc[f], 0, 0, 0);
    __syncthreads();  // publishes buf^1; buf reads complete before overwrite
  }

  // Partial logit over this wave's 64-col quarter.
  // C/D: hidden col = q*64 + f*16 + l15, row-in-tile = l16*4 + r.
  float part[4] = {0.f, 0.f, 0.f, 0.f};
#pragma unroll
  for (int f = 0; f < 4; ++f) {
    const int cc = (q << 6) + (f << 4) + l15;
    const float w2v = W2[cc];
    const float b1v = bias1[cc];
#pragma unroll
    for (int r = 0; r < 4; ++r) {
      const float hh = acc[f][r] + b1v;
      part[r] += (hh > 0.f) ? hh * w2v : 0.f;
    }
  }
#pragma unroll
  for (int r = 0; r < 4; ++r) {
#pragma unroll
    for (int m = 1; m < 16; m <<= 1) part[r] += __shfl_xor(part[r], m, 16);
  }
  if (l15 == 0) {
#pragma unroll
    for (int r = 0; r < 4; ++r)
      xs2[((s << 2) + q) * ROWS_PB + (l16 << 2) + r] = part[r];
  }
  __syncthreads();

  // Epilogue: 16 rows x 128 f32x4 = 2048 pieces / 512 threads = 4 each;
  // z re-read is L2-hot (this block just streamed these rows).
#pragma unroll
  for (int j = 0; j < 4; ++j) {
    const int idx = j * 512 + t;
    const int row = idx >> 7;
    const int c4 = idx & 127;
    const int grow = row0 + row;
    if (grow < n) {
      const float x = xs2[row] + xs2[16 + row] + xs2[32 + row] + xs2[48 + row];
      const float y = xs2[64 + row] + xs2[80 + row] + xs2[96 + row] +
                      xs2[112 + row];
      const float sx = 1.f / (1.f + __expf(y - x));  // b2 cancels
      const float sy = 1.f - sx;
      const size_t off = (size_t)grow * DIM + ((size_t)c4 << 2);
      const f32x4 a4 = *(const f32x4*)(z1 + off);
      const f32x4 b4 = *(const f32x4*)(z2 + off);
      f32x4 ov;
      ov[0] = sx * a4[0] + sy * b4[0];
      ov[1] = sx * a4[1] + sy * b4[1];
      ov[2] = sx * a4[2] + sy * b4[2];
      ov[3] = sx * a4[3] + sy * b4[3];
      *(f32x4*)(out + off) = ov;
    }
  }
}

extern "C" void kernel_launch(void* const* d_in, const int* in_sizes, int n_in,
                              void* d_out, int out_size, void* d_ws,
                              size_t ws_size, hipStream_t stream) {
  const float* z1 = (const float*)d_in[0];
  const float* z2 = (const float*)d_in[1];
  const float* W1 = (const float*)d_in[2];
  const float* b1 = (const float*)d_in[3];
  const float* W2 = (const float*)d_in[4];
  const float* b2 = (const float*)d_in[5];
  float* out = (float*)d_out;
  const int n = in_sizes[0] / DIM;
  unsigned short* w1s = (unsigned short*)d_ws;  // 512*256*2 = 256 KB

  hipLaunchKernelGGL(w1_swz_kernel, dim3((DIM * HID + 255) / 256), dim3(256),
                     0, stream, W1, w1s);
  const int nwg = (n + ROWS_PB - 1) / ROWS_PB;
  hipLaunchKernelGGL(fa_main_kernel, dim3(nwg), dim3(512), 0, stream, z1, z2,
                     w1s, b1, W2, b2, out, n);
}

// Round 22
// 187.290 us; speedup vs baseline: 2.2514x; 2.2514x over previous
//
#include <hip/hip_runtime.h>
#include <hip/hip_bf16.h>
#include <cmath>

#define DIM 512
#define HID 256
#define ROWS_PB 32       // rows per block (100000 = 3125 * 32, no tail)
#define NCHUNK 16        // K chunks of 32
#define CB 16384         // B chunk bytes: 32k * 256c * 2B

typedef __attribute__((ext_vector_type(8))) short short8;
typedef __attribute__((ext_vector_type(4))) float f32x4;
typedef __attribute__((ext_vector_type(4))) unsigned int u32x4;

__device__ __forceinline__ unsigned short f2bf(float f) {
  union { float f; unsigned u; } v; v.f = f;
  unsigned u = v.u;
  return (unsigned short)((u + 0x7FFFu + ((u >> 16) & 1u)) >> 16);
}
__device__ __forceinline__ float bf2f(short h) {
  union { unsigned u; float f; } v;
  v.u = ((unsigned)(unsigned short)h) << 16;
  return v.f;
}

// LDS-only barrier: waits local (ds) ops, syncs waves, fences the
// scheduler — but does NOT drain vmcnt, so register-destined global loads
// (T14 breg staging) stay in flight across it. The only cross-wave shared
// state in the K-loop is LDS, so lgkmcnt+barrier is sufficient ordering;
// breg consumption is wave-private and ordered by the compiler's own
// vmcnt tracking.
#define LGKM_BAR()                                        \
  do {                                                    \
    asm volatile("s_waitcnt lgkmcnt(0)" ::: "memory");    \
    __builtin_amdgcn_s_barrier();                         \
    __builtin_amdgcn_sched_barrier(0);                    \
  } while (0)

// Pre-swizzle W1 (fp32 [512,256] row-major) into bf16 MFMA fragment order:
// w1s[((k>>3)*HID + c)*8 + (k&7)]. K-chunk c (32 k's) is the contiguous
// 16 KB at byte offset c*16384 — a linear copy.
__global__ void w1_swz_kernel(const float* __restrict__ W1,
                              unsigned short* __restrict__ w1s) {
  int tid = blockIdx.x * blockDim.x + threadIdx.x;
  if (tid >= DIM * HID) return;
  int k = tid / HID;
  int c = tid - k * HID;
  w1s[(((k >> 3) * HID) + c) * 8 + (k & 7)] = f2bf(W1[tid]);
}

__device__ __forceinline__ short8 cvt8(const f32x4 p0, const f32x4 p1) {
  short8 r;
  r[0] = (short)f2bf(p0[0]); r[1] = (short)f2bf(p0[1]);
  r[2] = (short)f2bf(p0[2]); r[3] = (short)f2bf(p0[3]);
  r[4] = (short)f2bf(p1[0]); r[5] = (short)f2bf(p1[1]);
  r[6] = (short)f2bf(p1[2]); r[7] = (short)f2bf(p1[3]);
  return r;
}

__device__ __forceinline__ void wcombine(float wa, const short8 a, float wb,
                                         const short8 b, f32x4& o0, f32x4& o1) {
#pragma unroll
  for (int i = 0; i < 4; ++i) {
    o0[i] = wa * bf2f(a[i]) + wb * bf2f(b[i]);
    o1[i] = wa * bf2f(a[i + 4]) + wb * bf2f(b[i + 4]);
  }
}

// R13/R18 structure with LDS-only K-loop barriers: BLOAD(c+1) (L2 -> regs)
// survives both barriers and is consumed by BWRITE one chunk later — the
// per-chunk L2-latency exposure that capped every prior variant is gone.
__global__ __launch_bounds__(256, 2) void fa_main_kernel(
    const float* __restrict__ z1, const float* __restrict__ z2,
    const unsigned short* __restrict__ w1s,
    const float* __restrict__ bias1, const float* __restrict__ W2,
    const float* __restrict__ bias2, float* __restrict__ out, int n) {
  // Az [src][chunk][tile][lane] short8 = 64 KB; Bs 16 KB single buffer
  // (xs aliases Bs after the K-loop). Total 80 KB -> 2 blocks/CU.
  __shared__ char smem[81920];
  short8* Az = (short8*)smem;
  char* Bs = smem + 65536;
  float* xs = (float*)(smem + 65536);  // [src][32 rows], post-K-loop only

  const int t = threadIdx.x;
  const int w = t >> 6;
  const int l = t & 63;
  const int l15 = l & 15, l16 = l >> 4;
  const int s = w & 1;    // source
  const int tl = w >> 1;  // row tile 0..1
  const int row0 = blockIdx.x * ROWS_PB;
  const int myrow = row0 + tl * 16 + l15;
  const bool rok = myrow < n;
  const float* zz = s ? z2 : z1;
  const float* ap = zz + (size_t)myrow * DIM + (l16 << 3);
  const f32x4 zf4 = (f32x4){0.f, 0.f, 0.f, 0.f};

  // T14 B-staging: 16 KB/chunk = 4 x u32x4 per thread (wave-private regs).
  u32x4 breg0, breg1, breg2, breg3;
#define BLOAD(c)                                            \
  {                                                         \
    const u32x4* g = (const u32x4*)w1s + (c) * 1024 + t;    \
    breg0 = g[0];                                           \
    breg1 = g[256];                                         \
    breg2 = g[512];                                         \
    breg3 = g[768];                                         \
  }
#define BWRITE()                                            \
  {                                                         \
    u32x4* d = (u32x4*)Bs + t;                              \
    d[0] = breg0;                                           \
    d[256] = breg1;                                         \
    d[512] = breg2;                                         \
    d[768] = breg3;                                         \
  }

  // ---- Phase 1: B[0] issue, then the A burst (4 groups x 8 indep loads).
  BLOAD(0);
  __builtin_amdgcn_sched_barrier(0);
#pragma unroll
  for (int g = 0; g < 4; ++g) {
    f32x4 p[4][2];
#pragma unroll
    for (int j = 0; j < 4; ++j) {
      const float* pp = ap + (((g << 2) + j) << 5);
      p[j][0] = rok ? *(const f32x4*)(pp) : zf4;
      p[j][1] = rok ? *(const f32x4*)(pp + 4) : zf4;
    }
#pragma unroll
    for (int j = 0; j < 4; ++j)
      Az[((s * NCHUNK + (g << 2) + j) * 2 + tl) * 64 + l] =
          cvt8(p[j][0], p[j][1]);
  }
  BWRITE();         // waits only breg (its own dataflow)
  __syncthreads();  // prologue: full drain once is fine

  f32x4 acc[16];
#pragma unroll
  for (int f = 0; f < 16; ++f) acc[f] = zf4;

  // ---- Phase 2: K-loop. LDS-only barriers; BLOAD(c+1) in flight ~2
  // barrier periods before its BWRITE consumes it.
#pragma unroll
  for (int c = 0; c < NCHUNK; ++c) {
    if (c + 1 < NCHUNK) BLOAD(c + 1);  // L2 -> regs, survives the barriers
    __builtin_amdgcn_sched_barrier(0);
    // Batched fragment reads: af + 16 B-frags, all in flight together.
    const short8* bp = (const short8*)Bs + (l16 << 8) + l15;
    const short8 af = Az[((s * NCHUNK + c) * 2 + tl) * 64 + l];
    short8 bf[16];
#pragma unroll
    for (int f = 0; f < 16; ++f) bf[f] = bp[f << 4];
    __builtin_amdgcn_sched_barrier(0);  // reads above, MFMAs below
#pragma unroll
    for (int f = 0; f < 16; ++f)
      acc[f] =
          __builtin_amdgcn_mfma_f32_16x16x32_bf16(af, bf[f], acc[f], 0, 0, 0);
    LGKM_BAR();  // all waves' Bs reads retired; vmem stays in flight
    if (c + 1 < NCHUNK) BWRITE();  // ds_write; own vmcnt wait on breg
    LGKM_BAR();  // Bs writes visible block-wide
  }

  // ---- Phase 3a: full logit per wave. C/D: col = f*16+l15, row = l16*4+r.
  float part[4] = {0.f, 0.f, 0.f, 0.f};
#pragma unroll
  for (int f = 0; f < 16; ++f) {
    const int cc = (f << 4) + l15;
    const float w2v = W2[cc];
    const float b1v = bias1[cc];
#pragma unroll
    for (int r = 0; r < 4; ++r) {
      const float hh = acc[f][r] + b1v;
      part[r] += (hh > 0.f) ? hh * w2v : 0.f;
    }
  }
#pragma unroll
  for (int r = 0; r < 4; ++r) {
#pragma unroll
    for (int m = 1; m < 16; m <<= 1) part[r] += __shfl_xor(part[r], m, 16);
  }
  if (l15 == 0) {
#pragma unroll
    for (int r = 0; r < 4; ++r)
      xs[s * ROWS_PB + tl * 16 + (l16 << 2) + r] = part[r];
  }
  __syncthreads();

  // ---- Phase 3b: scores + output, entirely from Az (no HBM reads).
  const float x = xs[tl * 16 + l15];
  const float y = xs[ROWS_PB + tl * 16 + l15];
  const float sx = 1.f / (1.f + __expf(y - x));  // b2 cancels
  const float sy = 1.f - sx;
  float* orow = out + (size_t)myrow * DIM + (l16 << 3);
  if (rok) {
#pragma unroll
    for (int j = 0; j < 8; ++j) {
      const int cc = (s << 3) + j;  // this wave covers column chunks s*8..+8
      const short8 a0 = Az[((0 * NCHUNK + cc) * 2 + tl) * 64 + l];
      const short8 a1 = Az[((1 * NCHUNK + cc) * 2 + tl) * 64 + l];
      f32x4 o0, o1;
      wcombine(sx, a0, sy, a1, o0, o1);
      *(f32x4*)(orow + (cc << 5)) = o0;
      *(f32x4*)(orow + (cc << 5) + 4) = o1;
    }
  }
#undef BLOAD
#undef BWRITE
}

extern "C" void kernel_launch(void* const* d_in, const int* in_sizes, int n_in,
                              void* d_out, int out_size, void* d_ws,
                              size_t ws_size, hipStream_t stream) {
  const float* z1 = (const float*)d_in[0];
  const float* z2 = (const float*)d_in[1];
  const float* W1 = (const float*)d_in[2];
  const float* b1 = (const float*)d_in[3];
  const float* W2 = (const float*)d_in[4];
  const float* b2 = (const float*)d_in[5];
  float* out = (float*)d_out;
  const int n = in_sizes[0] / DIM;
  unsigned short* w1s = (unsigned short*)d_ws;  // 512*256*2 = 256 KB

  hipLaunchKernelGGL(w1_swz_kernel, dim3((DIM * HID + 255) / 256), dim3(256),
                     0, stream, W1, w1s);
  const int nwg = (n + ROWS_PB - 1) / ROWS_PB;
  hipLaunchKernelGGL(fa_main_kernel, dim3(nwg), dim3(256), 0, stream, z1, z2,
                     w1s, b1, W2, b2, out, n);
}

// Round 23
// 183.274 us; speedup vs baseline: 2.3007x; 1.0219x over previous
//
#include <hip/hip_runtime.h>
#include <hip/hip_bf16.h>
#include <cmath>

#define DIM 512
#define HID 256
#define ROWS_PB 32       // rows per block (100000 = 3125 * 32, no tail)
#define NCHUNK 16        // K chunks of 32
#define CB 16384         // B chunk bytes: 32k * 256c * 2B

typedef __attribute__((ext_vector_type(8))) short short8;
typedef __attribute__((ext_vector_type(4))) float f32x4;
typedef __attribute__((ext_vector_type(4))) unsigned int u32x4;

__device__ __forceinline__ unsigned short f2bf(float f) {
  union { float f; unsigned u; } v; v.f = f;
  unsigned u = v.u;
  return (unsigned short)((u + 0x7FFFu + ((u >> 16) & 1u)) >> 16);
}
__device__ __forceinline__ float bf2f(short h) {
  union { unsigned u; float f; } v;
  v.u = ((unsigned)(unsigned short)h) << 16;
  return v.f;
}

// LDS-only barrier (R22-verified): waits ds ops, syncs waves, fences the
// scheduler — but does NOT drain vmcnt, so in-flight global loads (A-stream
// to regs, B breg staging) survive it. All cross-wave K-loop state is LDS,
// so this is sufficient ordering; reg-destined loads are wave-private and
// ordered by the compiler's own vmcnt tracking.
#define LGKM_BAR()                                        \
  do {                                                    \
    asm volatile("s_waitcnt lgkmcnt(0)" ::: "memory");    \
    __builtin_amdgcn_s_barrier();                         \
    __builtin_amdgcn_sched_barrier(0);                    \
  } while (0)

// Pre-swizzle W1 (fp32 [512,256] row-major) into bf16 MFMA fragment order:
// w1s[((k>>3)*HID + c)*8 + (k&7)]. K-chunk c (32 k's) is the contiguous
// 16 KB at byte offset c*16384 — a linear copy.
__global__ void w1_swz_kernel(const float* __restrict__ W1,
                              unsigned short* __restrict__ w1s) {
  int tid = blockIdx.x * blockDim.x + threadIdx.x;
  if (tid >= DIM * HID) return;
  int k = tid / HID;
  int c = tid - k * HID;
  w1s[(((k >> 3) * HID) + c) * 8 + (k & 7)] = f2bf(W1[tid]);
}

__device__ __forceinline__ short8 cvt8(const f32x4 p0, const f32x4 p1) {
  short8 r;
  r[0] = (short)f2bf(p0[0]); r[1] = (short)f2bf(p0[1]);
  r[2] = (short)f2bf(p0[2]); r[3] = (short)f2bf(p0[3]);
  r[4] = (short)f2bf(p1[0]); r[5] = (short)f2bf(p1[1]);
  r[6] = (short)f2bf(p1[2]); r[7] = (short)f2bf(p1[3]);
  return r;
}

__device__ __forceinline__ void wcombine(float wa, const short8 a, float wb,
                                         const short8 b, f32x4& o0, f32x4& o1) {
#pragma unroll
  for (int i = 0; i < 4; ++i) {
    o0[i] = wa * bf2f(a[i]) + wb * bf2f(b[i]);
    o1[i] = wa * bf2f(a[i + 4]) + wb * bf2f(b[i + 4]);
  }
}

// R22 structure + A STREAMED THROUGH THE K-LOOP (anti-phase-convoy):
// per chunk the wave loads A(c+2) from HBM into a 2-slot register pipe,
// cvt's A(c) and ds_writes it to Az (for the epilogue). LGKM-only barriers
// keep those HBM loads in flight across chunk boundaries — the block issues
// HBM reads continuously instead of a front-loaded burst, so co-resident
// blocks no longer alternate HBM-idle / HBM-burst convoys.
__global__ __launch_bounds__(256, 2) void fa_main_kernel(
    const float* __restrict__ z1, const float* __restrict__ z2,
    const unsigned short* __restrict__ w1s,
    const float* __restrict__ bias1, const float* __restrict__ W2,
    const float* __restrict__ bias2, float* __restrict__ out, int n) {
  // Az [src][chunk][tile][lane] short8 = 64 KB; Bs 16 KB single buffer
  // (xs aliases Bs after the K-loop). Total 80 KB -> 2 blocks/CU.
  __shared__ char smem[81920];
  short8* Az = (short8*)smem;
  char* Bs = smem + 65536;
  float* xs = (float*)(smem + 65536);  // [src][32 rows], post-K-loop only

  const int t = threadIdx.x;
  const int w = t >> 6;
  const int l = t & 63;
  const int l15 = l & 15, l16 = l >> 4;
  const int s = w & 1;    // source
  const int tl = w >> 1;  // row tile 0..1
  const int row0 = blockIdx.x * ROWS_PB;
  const int myrow = row0 + tl * 16 + l15;
  const bool rok = myrow < n;
  const float* zz = s ? z2 : z1;
  const float* ap = zz + (size_t)myrow * DIM + (l16 << 3);
  const f32x4 zf4 = (f32x4){0.f, 0.f, 0.f, 0.f};

  // T14 B-staging: 16 KB/chunk = 4 x u32x4 per thread (wave-private regs).
  u32x4 breg0, breg1, breg2, breg3;
#define BLOAD(c)                                            \
  {                                                         \
    const u32x4* g = (const u32x4*)w1s + (c) * 1024 + t;    \
    breg0 = g[0];                                           \
    breg1 = g[256];                                         \
    breg2 = g[512];                                         \
    breg3 = g[768];                                         \
  }
#define BWRITE()                                            \
  {                                                         \
    u32x4* d = (u32x4*)Bs + t;                              \
    d[0] = breg0;                                           \
    d[256] = breg1;                                         \
    d[512] = breg2;                                         \
    d[768] = breg3;                                         \
  }

  // ---- Prologue: B[0] + A(0),A(1) into the 2-slot pipe; one full drain.
  BLOAD(0);
  f32x4 paA0, paA1, paB0, paB1;  // slots: even chunks (A), odd chunks (B)
  paA0 = rok ? *(const f32x4*)(ap) : zf4;
  paA1 = rok ? *(const f32x4*)(ap + 4) : zf4;
  paB0 = rok ? *(const f32x4*)(ap + 32) : zf4;
  paB1 = rok ? *(const f32x4*)(ap + 36) : zf4;
  BWRITE();
  __syncthreads();  // Bs[0] visible (A(0),A(1) also landed — fine)

  f32x4 acc[16];
#pragma unroll
  for (int f = 0; f < 16; ++f) acc[f] = zf4;

  // ---- K-loop: continuous HBM A-stream + LDS-only barriers.
#pragma unroll
  for (int c = 0; c < NCHUNK; ++c) {
    if (c + 1 < NCHUNK) BLOAD(c + 1);  // L2 -> regs, survives barriers
    // A(c): cvt from this chunk's slot; park in Az for the epilogue.
    short8 af;
    if (c & 1)
      af = cvt8(paB0, paB1);
    else
      af = cvt8(paA0, paA1);
    Az[((s * NCHUNK + c) * 2 + tl) * 64 + l] = af;
    // A(c+2): refill the slot just consumed (HBM, ~2 chunk periods ahead).
    if (c + 2 < NCHUNK) {
      const float* apn = ap + ((c + 2) << 5);
      if (c & 1) {
        paB0 = rok ? *(const f32x4*)(apn) : zf4;
        paB1 = rok ? *(const f32x4*)(apn + 4) : zf4;
      } else {
        paA0 = rok ? *(const f32x4*)(apn) : zf4;
        paA1 = rok ? *(const f32x4*)(apn + 4) : zf4;
      }
    }
    __builtin_amdgcn_sched_barrier(0);
    // Batched B-fragment reads, then the MFMA cluster (R22-proven).
    const short8* bp = (const short8*)Bs + (l16 << 8) + l15;
    short8 bf[16];
#pragma unroll
    for (int f = 0; f < 16; ++f) bf[f] = bp[f << 4];
    __builtin_amdgcn_sched_barrier(0);
#pragma unroll
    for (int f = 0; f < 16; ++f)
      acc[f] =
          __builtin_amdgcn_mfma_f32_16x16x32_bf16(af, bf[f], acc[f], 0, 0, 0);
    LGKM_BAR();  // Bs reads + Az write retired; vmem stays in flight
    if (c + 1 < NCHUNK) BWRITE();  // ds_write; own vmcnt wait on breg
    LGKM_BAR();  // Bs writes visible block-wide
  }

  // ---- Logits. C/D: col = f*16+l15, row-in-tile = l16*4+r.
  float part[4] = {0.f, 0.f, 0.f, 0.f};
#pragma unroll
  for (int f = 0; f < 16; ++f) {
    const int cc = (f << 4) + l15;
    const float w2v = W2[cc];
    const float b1v = bias1[cc];
#pragma unroll
    for (int r = 0; r < 4; ++r) {
      const float hh = acc[f][r] + b1v;
      part[r] += (hh > 0.f) ? hh * w2v : 0.f;
    }
  }
#pragma unroll
  for (int r = 0; r < 4; ++r) {
#pragma unroll
    for (int m = 1; m < 16; m <<= 1) part[r] += __shfl_xor(part[r], m, 16);
  }
  if (l15 == 0) {
#pragma unroll
    for (int r = 0; r < 4; ++r)
      xs[s * ROWS_PB + tl * 16 + (l16 << 2) + r] = part[r];
  }
  __syncthreads();

  // ---- Epilogue: scores + output, entirely from Az (no HBM reads).
  const float x = xs[tl * 16 + l15];
  const float y = xs[ROWS_PB + tl * 16 + l15];
  const float sx = 1.f / (1.f + __expf(y - x));  // b2 cancels
  const float sy = 1.f - sx;
  float* orow = out + (size_t)myrow * DIM + (l16 << 3);
  if (rok) {
#pragma unroll
    for (int j = 0; j < 8; ++j) {
      const int cc = (s << 3) + j;  // this wave covers column chunks s*8..+8
      const short8 a0 = Az[((0 * NCHUNK + cc) * 2 + tl) * 64 + l];
      const short8 a1 = Az[((1 * NCHUNK + cc) * 2 + tl) * 64 + l];
      f32x4 o0, o1;
      wcombine(sx, a0, sy, a1, o0, o1);
      *(f32x4*)(orow + (cc << 5)) = o0;
      *(f32x4*)(orow + (cc << 5) + 4) = o1;
    }
  }
#undef BLOAD
#undef BWRITE
}

extern "C" void kernel_launch(void* const* d_in, const int* in_sizes, int n_in,
                              void* d_out, int out_size, void* d_ws,
                              size_t ws_size, hipStream_t stream) {
  const float* z1 = (const float*)d_in[0];
  const float* z2 = (const float*)d_in[1];
  const float* W1 = (const float*)d_in[2];
  const float* b1 = (const float*)d_in[3];
  const float* W2 = (const float*)d_in[4];
  const float* b2 = (const float*)d_in[5];
  float* out = (float*)d_out;
  const int n = in_sizes[0] / DIM;
  unsigned short* w1s = (unsigned short*)d_ws;  // 512*256*2 = 256 KB

  hipLaunchKernelGGL(w1_swz_kernel, dim3((DIM * HID + 255) / 256), dim3(256),
                     0, stream, W1, w1s);
  const int nwg = (n + ROWS_PB - 1) / ROWS_PB;
  hipLaunchKernelGGL(fa_main_kernel, dim3(nwg), dim3(256), 0, stream, z1, z2,
                     w1s, b1, W2, b2, out, n);
}